// Round 3
// baseline (422.691 us; speedup 1.0000x reference)
//
#include <hip/hip_runtime.h>

typedef __attribute__((ext_vector_type(8))) short bf16x8;
typedef __attribute__((ext_vector_type(4))) float f32x4;
typedef unsigned short u16;
typedef unsigned int u32;

#define NTOK 144
#define CDIM 192
#define NH 6
#define CH 32
#define C3 576
#define NWIN 64
#define WLON 15
#define SCALE 0.17677669529663687f
#define LOG2E 1.4426950408889634f

// ws layout (bytes)
#define OFF_W1T  0u            // 576*192*2 = 221184
#define OFF_W2T  221184u       // 192*192*2 = 73728
#define OFF_COMB 294912u       // 384*81*64*4*2 = 15925248 (frag layout)
#define OFF_Q    16220160u     // 960*6*144*32*2 = 53084160
#define OFF_K    69304320u
#define OFF_V    122388480u    // stored transposed: [b][h][ch][144]

__device__ __forceinline__ u16 f2b(float f){
  u32 u = __float_as_uint(f);
  u32 r = u + 0x7FFFu + ((u >> 16) & 1u);   // RNE
  return (u16)(r >> 16);
}
__device__ __forceinline__ float b2f(u16 u){
  return __uint_as_float(((u32)u) << 16);
}
__device__ __forceinline__ u32 pk2(float a, float b){
  return (u32)f2b(a) | ((u32)f2b(b) << 16);
}

// ---------------- prep: transpose weights to bf16 (B-operand wants k-contiguous rows)
extern "C" __global__ __launch_bounds__(256) void prep_weights(
    const float* __restrict__ w1, const float* __restrict__ w2,
    u16* __restrict__ w1t, u16* __restrict__ w2t){
  int idx = blockIdx.x * 256 + threadIdx.x;
  if (idx < CDIM * C3){ int k = idx / C3;  int c = idx - k * C3;  w1t[c * CDIM + k] = f2b(w1[idx]); }
  if (idx < CDIM * CDIM){ int k = idx / CDIM; int c = idx - k * CDIM; w2t[c * CDIM + k] = f2b(w2[idx]); }
}

// ---------------- prep: comb in MFMA C-fragment layout:
// comb[nwh][ti(9)][nt(9)][lane(64)][r(4)] = bias_table[pidx[i*144+j]][nw][h] + mask[nw*15][i][j]
extern "C" __global__ __launch_bounds__(192) void prep_comb(
    const float* __restrict__ bt, const float* __restrict__ mask,
    const int* __restrict__ pidx, u16* __restrict__ comb){
  int nwh = blockIdx.x;                 // 0..383 = nw*6+h
  int nw = nwh / NH, h = nwh - nw * NH;
  int tl = blockIdx.y * 192 + threadIdx.x;   // 0..5183 = (ti*9+nt)*64+lane
  int ti = tl / 576;
  int rem = tl - ti * 576;
  int nt = rem >> 6, lane = rem & 63;
  int ib = ti * 16 + ((lane >> 4) << 2);
  int j  = nt * 16 + (lane & 15);
  const float* mrow = mask + (size_t)(nw * WLON) * (NTOK * NTOK);
  float v[4];
  #pragma unroll
  for (int r = 0; r < 4; ++r){
    int e = (ib + r) * NTOK + j;
    int pi = pidx[e];
    v[r] = bt[((size_t)pi * NWIN + nw) * NH + h] + mrow[e];
  }
  uint2 out; out.x = pk2(v[0], v[1]); out.y = pk2(v[2], v[3]);
  *reinterpret_cast<uint2*>(comb + ((size_t)nwh * 5184 + tl) * 4) = out;
}

// ---------------- K1: qkv = x @ w1 + b1 — LDS-free, barrier-free.
// Each wave owns 32 rows; A fragments (fp32->bf16) live in registers for all 576 cols.
// B fragments read directly from global (64x192 panel = 24.6 KB -> L1-resident per block).
extern "C" __global__ __launch_bounds__(256, 3) void qkv_gemm(
    const float* __restrict__ x, const u16* __restrict__ w1t, const float* __restrict__ b1,
    u16* __restrict__ qw, u16* __restrict__ kw, u16* __restrict__ vw){
  const int tid = threadIdx.x;
  const int wid = tid >> 6, lane = tid & 63, l15 = lane & 15, l4 = lane >> 4;
  const size_t row0 = (size_t)blockIdx.x * 128 + wid * 32;
  const f32x4 zz = {0.f, 0.f, 0.f, 0.f};

  // A fragments: rows row0 + mf*16 + l15, k = kk*32 + l4*8 (2x float4 -> bf16x8)
  bf16x8 af[2][6];
  #pragma unroll
  for (int mf = 0; mf < 2; ++mf){
    const float* src = x + (row0 + mf * 16 + l15) * CDIM + l4 * 8;
    #pragma unroll
    for (int kk = 0; kk < 6; ++kk){
      float4 f0 = *reinterpret_cast<const float4*>(src + kk * 32);
      float4 f1 = *reinterpret_cast<const float4*>(src + kk * 32 + 4);
      union { bf16x8 v; uint4 u; } cv;
      cv.u.x = pk2(f0.x, f0.y); cv.u.y = pk2(f0.z, f0.w);
      cv.u.z = pk2(f1.x, f1.y); cv.u.w = pk2(f1.z, f1.w);
      af[mf][kk] = cv.v;
    }
  }

  #pragma unroll 1
  for (int nt = 0; nt < 9; ++nt){
    f32x4 acc[2][4];
    #pragma unroll
    for (int mf = 0; mf < 2; ++mf)
      #pragma unroll
      for (int nf = 0; nf < 4; ++nf) acc[mf][nf] = zz;
    #pragma unroll
    for (int kk = 0; kk < 6; ++kk){
      bf16x8 bfr[4];
      #pragma unroll
      for (int nf = 0; nf < 4; ++nf)
        bfr[nf] = *reinterpret_cast<const bf16x8*>(
            w1t + (size_t)(nt * 64 + nf * 16 + l15) * CDIM + kk * 32 + l4 * 8);
      #pragma unroll
      for (int mf = 0; mf < 2; ++mf)
        #pragma unroll
        for (int nf = 0; nf < 4; ++nf)
          acc[mf][nf] = __builtin_amdgcn_mfma_f32_16x16x32_bf16(af[mf][kk], bfr[nf], acc[mf][nf], 0, 0, 0);
    }
    // epilogue: nt 0-2 -> Q, 3-5 -> K, 6-8 -> V (64-col tiles never straddle)
    int which = nt / 3;
    u16* base = (which == 0) ? qw : ((which == 1) ? kw : vw);
    float mult = (which == 0) ? SCALE : 1.0f;
    #pragma unroll
    for (int nf = 0; nf < 4; ++nf){
      int c = nt * 64 + nf * 16 + l15;
      int rem = c - which * CDIM;
      int hh = rem >> 5, chh = rem & 31;
      float bias = b1[c];
      #pragma unroll
      for (int mf = 0; mf < 2; ++mf){
        #pragma unroll
        for (int r = 0; r < 4; ++r){
          int t = (int)row0 + mf * 16 + l4 * 4 + r;
          int bwin = t / NTOK;
          int n = t - bwin * NTOK;
          float v = (acc[mf][nf][r] + bias) * mult;
          size_t addr = (which == 2)
            ? ((((size_t)bwin * NH + hh) * CH + chh) * NTOK + n)    // V transposed
            : ((((size_t)bwin * NH + hh) * NTOK + n) * CH + chh);   // Q/K row-major
          base[addr] = f2b(v);
        }
      }
    }
  }
}

// ---------------- K2: per (window, head) attention — no barriers, no staging LDS.
extern "C" __global__ __launch_bounds__(192, 4) void attn_kernel(
    const u16* __restrict__ qw, const u16* __restrict__ kw, const u16* __restrict__ vw,
    const u16* __restrict__ comb, float* __restrict__ outbuf){
  __shared__ u16 Pl[3][16][40];   // per-wave P chunk, pad 40 (80B rows -> 8 bank groups)
  const int tid = threadIdx.x;
  const int bh = blockIdx.x;
  const int b = bh / NH, h = bh - b * NH;
  const int wv = tid >> 6, lane = tid & 63, l15 = lane & 15, l4 = lane >> 4;
  const size_t qkbase = ((size_t)b * NH + h) * (NTOK * CH);
  const size_t vbase  = ((size_t)b * NH + h) * (CH * NTOK);
  const size_t cbase  = ((size_t)((b / WLON) * NH + h)) * (5184 * 4);  // u16 units
  u16* Pw = &Pl[wv][0][0];
  u16* stash = reinterpret_cast<u16*>(outbuf);
  const f32x4 zz = {0.f, 0.f, 0.f, 0.f};

  for (int mi = 0; mi < 3; ++mi){
    const int ti = wv * 3 + mi;
    bf16x8 aq = *reinterpret_cast<const bf16x8*>(qw + qkbase + (ti * 16 + l15) * CH + l4 * 8);
    f32x4 s[9];
    #pragma unroll
    for (int nt = 0; nt < 9; ++nt){
      bf16x8 bk = *reinterpret_cast<const bf16x8*>(kw + qkbase + (nt * 16 + l15) * CH + l4 * 8);
      s[nt] = __builtin_amdgcn_mfma_f32_16x16x32_bf16(aq, bk, zz, 0, 0, 0);
    }
    #pragma unroll
    for (int nt = 0; nt < 9; ++nt){
      uint2 cc = *reinterpret_cast<const uint2*>(comb + cbase + ((size_t)(ti * 9 + nt) * 64 + lane) * 4);
      s[nt][0] += b2f((u16)(cc.x & 0xFFFF));
      s[nt][1] += b2f((u16)(cc.x >> 16));
      s[nt][2] += b2f((u16)(cc.y & 0xFFFF));
      s[nt][3] += b2f((u16)(cc.y >> 16));
    }
    float invs[4];
    #pragma unroll
    for (int r = 0; r < 4; ++r){
      float mx = s[0][r];
      #pragma unroll
      for (int nt = 1; nt < 9; ++nt) mx = fmaxf(mx, s[nt][r]);
      #pragma unroll
      for (int off = 8; off; off >>= 1) mx = fmaxf(mx, __shfl_xor(mx, off, 16));
      float sum = 0.f;
      #pragma unroll
      for (int nt = 0; nt < 9; ++nt){
        float p = exp2f((s[nt][r] - mx) * LOG2E);
        s[nt][r] = p; sum += p;
      }
      #pragma unroll
      for (int off = 8; off; off >>= 1) sum += __shfl_xor(sum, off, 16);
      invs[r] = 1.0f / sum;   // applied at stash
    }
    f32x4 o0 = zz, o1 = zz;
    #pragma unroll
    for (int kk = 0; kk < 5; ++kk){
      #pragma unroll
      for (int r = 0; r < 4; ++r){
        Pw[(l4 * 4 + r) * 40 + l15] = f2b(s[2 * kk][r]);
        if (kk < 4) Pw[(l4 * 4 + r) * 40 + 16 + l15] = f2b(s[2 * kk + 1][r]);
      }
      int j0 = kk * 32 + l4 * 8;
      int jc = (j0 < NTOK) ? j0 : 0;          // clamp tail address (stay in-bounds)
      bf16x8 ap = *reinterpret_cast<const bf16x8*>(Pw + l15 * 40 + l4 * 8);
      bf16x8 bv0 = *reinterpret_cast<const bf16x8*>(vw + vbase + (size_t)l15 * NTOK + jc);
      bf16x8 bv1 = *reinterpret_cast<const bf16x8*>(vw + vbase + (size_t)(16 + l15) * NTOK + jc);
      if (j0 >= NTOK) ap = bf16x8{0, 0, 0, 0, 0, 0, 0, 0};   // tail K=16: zero P side
      o0 = __builtin_amdgcn_mfma_f32_16x16x32_bf16(ap, bv0, o0, 0, 0, 0);
      o1 = __builtin_amdgcn_mfma_f32_16x16x32_bf16(ap, bv1, o1, 0, 0, 0);
    }
    #pragma unroll
    for (int r = 0; r < 4; ++r){
      size_t t = (size_t)b * NTOK + ti * 16 + l4 * 4 + r;
      float is = invs[r];
      stash[t * 384 + 192 + h * CH + l15]      = f2b(o0[r] * is);
      stash[t * 384 + 192 + h * CH + 16 + l15] = f2b(o1[r] * is);
    }
  }
}

// ---------------- K3: out = attn_out @ w2 + b2 — LDS-free, barrier-free (same skeleton as K1).
// Reads bf16 stash from upper half of d_out rows (own rows only), writes fp32 d_out.
extern "C" __global__ __launch_bounds__(256, 3) void proj_gemm(
    const u16* __restrict__ w2t, const float* __restrict__ b2, float* outbuf){
  const int tid = threadIdx.x;
  const int wid = tid >> 6, lane = tid & 63, l15 = lane & 15, l4 = lane >> 4;
  const size_t row0 = (size_t)blockIdx.x * 128 + wid * 32;
  const u16* stash = reinterpret_cast<const u16*>(outbuf);
  const f32x4 zz = {0.f, 0.f, 0.f, 0.f};

  // A fragments from stash (already bf16, 16B/lane)
  bf16x8 af[2][6];
  #pragma unroll
  for (int mf = 0; mf < 2; ++mf){
    const u16* src = stash + (row0 + mf * 16 + l15) * 384 + 192 + l4 * 8;
    #pragma unroll
    for (int kk = 0; kk < 6; ++kk)
      af[mf][kk] = *reinterpret_cast<const bf16x8*>(src + kk * 32);
  }

  #pragma unroll 1
  for (int nt = 0; nt < 3; ++nt){
    f32x4 acc[2][4];
    #pragma unroll
    for (int mf = 0; mf < 2; ++mf)
      #pragma unroll
      for (int nf = 0; nf < 4; ++nf) acc[mf][nf] = zz;
    #pragma unroll
    for (int kk = 0; kk < 6; ++kk){
      bf16x8 bfr[4];
      #pragma unroll
      for (int nf = 0; nf < 4; ++nf)
        bfr[nf] = *reinterpret_cast<const bf16x8*>(
            w2t + (size_t)(nt * 64 + nf * 16 + l15) * CDIM + kk * 32 + l4 * 8);
      #pragma unroll
      for (int mf = 0; mf < 2; ++mf)
        #pragma unroll
        for (int nf = 0; nf < 4; ++nf)
          acc[mf][nf] = __builtin_amdgcn_mfma_f32_16x16x32_bf16(af[mf][kk], bfr[nf], acc[mf][nf], 0, 0, 0);
    }
    #pragma unroll
    for (int nf = 0; nf < 4; ++nf){
      int c = nt * 64 + nf * 16 + l15;
      float bias = b2[c];
      #pragma unroll
      for (int mf = 0; mf < 2; ++mf){
        #pragma unroll
        for (int r = 0; r < 4; ++r){
          size_t t = row0 + mf * 16 + l4 * 4 + r;
          outbuf[t * CDIM + c] = acc[mf][nf][r] + bias;
        }
      }
    }
  }
}

extern "C" void kernel_launch(void* const* d_in, const int* in_sizes, int n_in,
                              void* d_out, int out_size, void* d_ws, size_t ws_size,
                              hipStream_t stream){
  const float* x    = (const float*)d_in[0];
  const float* w1   = (const float*)d_in[1];
  const float* b1   = (const float*)d_in[2];
  const float* w2   = (const float*)d_in[3];
  const float* b2   = (const float*)d_in[4];
  const float* bt   = (const float*)d_in[5];
  const float* mask = (const float*)d_in[6];
  const int*   pidx = (const int*)d_in[7];
  (void)in_sizes; (void)n_in; (void)out_size; (void)ws_size;

  char* ws = (char*)d_ws;
  u16* w1t  = (u16*)(ws + OFF_W1T);
  u16* w2t  = (u16*)(ws + OFF_W2T);
  u16* comb = (u16*)(ws + OFF_COMB);
  u16* qw   = (u16*)(ws + OFF_Q);
  u16* kw   = (u16*)(ws + OFF_K);
  u16* vw   = (u16*)(ws + OFF_V);
  float* out = (float*)d_out;

  prep_weights<<<dim3(432), dim3(256), 0, stream>>>(w1, w2, w1t, w2t);
  prep_comb<<<dim3(384, 27), dim3(192), 0, stream>>>(bt, mask, pidx, comb);
  qkv_gemm<<<dim3(1080), dim3(256), 0, stream>>>(x, w1t, b1, qw, kw, vw);
  attn_kernel<<<dim3(5760), dim3(192), 0, stream>>>(qw, kw, vw, comb, out);
  proj_gemm<<<dim3(1080), dim3(256), 0, stream>>>(w2t, b2, out);
}